// Round 1
// baseline (1005.459 us; speedup 1.0000x reference)
//
#include <hip/hip_runtime.h>
#include <cstdint>
#include <cstddef>

#define IN_DIM   1024
#define OUT_DIM  1024
#define T_STEPS  512
#define B_TOTAL  64

#define BM 128
#define BN 128
#define BK 16

// Classic f32 tiled GEMM: C[m][o] = sum_k A[m][k] * W[o][k] + bias[o]
// A: [M][1024] row-major (x chunk), W: [1024][1024] row-major (o-major, k-contig)
// 256 threads, 8x8 register tile per thread, k-major LDS tiles.
__global__ __launch_bounds__(256, 2)
void gemm_xwT(const float* __restrict__ A,
              const float* __restrict__ W,
              const float* __restrict__ bias,
              float* __restrict__ C)
{
    __shared__ float As[BK][BM];
    __shared__ float Ws[BK][BN];

    const int tid = threadIdx.x;
    const int tx  = tid & 15;   // N dim
    const int ty  = tid >> 4;   // M dim
    const int bn  = blockIdx.x;
    const int bm  = blockIdx.y;

    const float* Ag = A + (size_t)(bm * BM) * IN_DIM;
    const float* Wg = W + (size_t)(bn * BN) * IN_DIM;

    float acc[8][8];
#pragma unroll
    for (int i = 0; i < 8; ++i)
#pragma unroll
        for (int j = 0; j < 8; ++j) acc[i][j] = 0.f;

    for (int k0 = 0; k0 < IN_DIM; k0 += BK) {
        // Stage A-tile (128x16) and W-tile (128x16), transposed to k-major in LDS.
#pragma unroll
        for (int i = 0; i < 2; ++i) {
            const int q  = tid + i * 256;      // 0..511
            const int r  = q >> 2;             // row 0..127
            const int kq = (q & 3) << 2;       // k sub-offset 0,4,8,12
            const float4 av = *reinterpret_cast<const float4*>(Ag + (size_t)r * IN_DIM + k0 + kq);
            As[kq + 0][r] = av.x; As[kq + 1][r] = av.y;
            As[kq + 2][r] = av.z; As[kq + 3][r] = av.w;
            const float4 wv = *reinterpret_cast<const float4*>(Wg + (size_t)r * IN_DIM + k0 + kq);
            Ws[kq + 0][r] = wv.x; Ws[kq + 1][r] = wv.y;
            Ws[kq + 2][r] = wv.z; Ws[kq + 3][r] = wv.w;
        }
        __syncthreads();

#pragma unroll
        for (int k = 0; k < BK; ++k) {
            float a[8], w[8];
            *reinterpret_cast<float4*>(&a[0]) = *reinterpret_cast<const float4*>(&As[k][ty * 4]);
            *reinterpret_cast<float4*>(&a[4]) = *reinterpret_cast<const float4*>(&As[k][ty * 4 + 64]);
            *reinterpret_cast<float4*>(&w[0]) = *reinterpret_cast<const float4*>(&Ws[k][tx * 4]);
            *reinterpret_cast<float4*>(&w[4]) = *reinterpret_cast<const float4*>(&Ws[k][tx * 4 + 64]);
#pragma unroll
            for (int i = 0; i < 8; ++i)
#pragma unroll
                for (int j = 0; j < 8; ++j)
                    acc[i][j] += a[i] * w[j];
        }
        __syncthreads();
    }

    // Epilogue: add bias, store two float4 per row.
    float bv[8];
    *reinterpret_cast<float4*>(&bv[0]) = *reinterpret_cast<const float4*>(bias + bn * BN + tx * 4);
    *reinterpret_cast<float4*>(&bv[4]) = *reinterpret_cast<const float4*>(bias + bn * BN + tx * 4 + 64);
#pragma unroll
    for (int i = 0; i < 8; ++i) {
        const int row = bm * BM + ty * 4 + (i & 3) + (i >> 2) * 64;
        float* Cr = C + (size_t)row * OUT_DIM + bn * BN;
        float4 v0 = { acc[i][0] + bv[0], acc[i][1] + bv[1], acc[i][2] + bv[2], acc[i][3] + bv[3] };
        float4 v1 = { acc[i][4] + bv[4], acc[i][5] + bv[5], acc[i][6] + bv[6], acc[i][7] + bv[7] };
        *reinterpret_cast<float4*>(Cr + tx * 4)      = v0;
        *reinterpret_cast<float4*>(Cr + tx * 4 + 64) = v1;
    }
}

// Sequential LIF scan over T for each (b, o). proj chunk covers `bc` batches.
// Consecutive threads -> consecutive o -> coalesced reads at each t.
__global__ __launch_bounds__(256)
void lif_scan(const float* __restrict__ proj,
              float* __restrict__ out_mem,
              float* __restrict__ out_spk,
              int b_off)
{
    const int tid = blockIdx.x * 256 + threadIdx.x;
    const int b = tid >> 10;          // batch within chunk
    const int o = tid & 1023;
    const float* p = proj + (size_t)b * (T_STEPS * OUT_DIM) + o;

    float mem = 0.f;
    float spk = 0.f;
#pragma unroll 8
    for (int t = 0; t < T_STEPS; ++t) {
        const float in = p[(size_t)t * OUT_DIM];
        mem = mem + (in - mem) * 0.5f;           // TAU = 2.0
        const bool fire = (mem >= 1.0f);         // THRESHOLD = 1.0
        spk = fire ? 1.0f : 0.0f;
        mem = fire ? 0.0f : mem;
    }
    const size_t oi = (size_t)(b_off + b) * OUT_DIM + o;
    out_mem[oi] = mem;
    out_spk[oi] = spk;
}

extern "C" void kernel_launch(void* const* d_in, const int* in_sizes, int n_in,
                              void* d_out, int out_size, void* d_ws, size_t ws_size,
                              hipStream_t stream)
{
    const float* x    = (const float*)d_in[0];   // [64][512][1024]
    const float* W    = (const float*)d_in[1];   // [1024][1024]
    const float* bias = (const float*)d_in[2];   // [1024]

    float* out_mem = (float*)d_out;                           // [64][1024]
    float* out_spk = out_mem + (size_t)B_TOTAL * OUT_DIM;     // [64][1024]
    float* proj    = (float*)d_ws;

    const size_t bytes_per_b = (size_t)T_STEPS * OUT_DIM * sizeof(float); // 2 MiB
    int Bc = (int)(ws_size / bytes_per_b);
    if (Bc > B_TOTAL) Bc = B_TOTAL;
    if (Bc < 1) Bc = 1;  // last resort; ws is expected to be >= 2 MiB

    for (int b0 = 0; b0 < B_TOTAL; b0 += Bc) {
        const int bc = (B_TOTAL - b0 < Bc) ? (B_TOTAL - b0) : Bc;
        dim3 ggrid(OUT_DIM / BN, (bc * T_STEPS) / BM);
        gemm_xwT<<<ggrid, 256, 0, stream>>>(
            x + (size_t)b0 * T_STEPS * IN_DIM, W, bias, proj);
        lif_scan<<<dim3((bc * OUT_DIM) / 256), 256, 0, stream>>>(
            proj, out_mem, out_spk, b0);
    }
}

// Round 2
// 468.866 us; speedup vs baseline: 2.1444x; 2.1444x over previous
//
#include <hip/hip_runtime.h>
#include <cstdint>
#include <cstddef>

typedef _Float16 f16;
typedef __attribute__((ext_vector_type(8))) _Float16 half8;
typedef __attribute__((ext_vector_type(4))) _Float16 half4;
typedef __attribute__((ext_vector_type(4))) float f32x4;

#define IN_DIM   1024
#define OUT_DIM  1024
#define T_STEPS  512
#define B_TOTAL  64

// Async global->LDS, 16B per lane. Dest must be wave-uniform base + lane*16.
#define GLDS16(g, l)                                                            \
    __builtin_amdgcn_global_load_lds(                                           \
        (const __attribute__((address_space(1))) void*)(g),                     \
        (__attribute__((address_space(3))) void*)(l), 16, 0, 0)

// ---------------------------------------------------------------------------
// Split f32 -> (hi, lo*2048) f16 pair.  x = hi + lo/2048 to ~22 significand
// bits; the 2048 pre-scale keeps lo parts in f16 normal range.
// ---------------------------------------------------------------------------
__global__ __launch_bounds__(256)
void split_f32_f16(const float* __restrict__ in,
                   f16* __restrict__ hi, f16* __restrict__ lo, int n4)
{
    const int i = blockIdx.x * 256 + threadIdx.x;
    if (i >= n4) return;
    const float4 v = reinterpret_cast<const float4*>(in)[i];
    const float xs[4] = { v.x, v.y, v.z, v.w };
    half4 h, l;
#pragma unroll
    for (int j = 0; j < 4; ++j) {
        const f16 hh = (f16)xs[j];
        h[j] = hh;
        l[j] = (f16)((xs[j] - (float)hh) * 2048.0f);
    }
    reinterpret_cast<half4*>(hi)[i] = h;
    reinterpret_cast<half4*>(lo)[i] = l;
}

// ---------------------------------------------------------------------------
// f16x3 split GEMM: C[m][o] = sum_k x[m][k] * W[o][k] + bias[o], f32-accurate.
//   accH += Ah*Bh ; accL += Al*Bh + Ah*Bl ; C = accH + accL/2048 + bias
// m97-style structure: 128x128 tile, BK=32, 4 waves, 16x16x32 f16 MFMA,
// linear LDS + global_load_lds(16B).
// ---------------------------------------------------------------------------
__global__ __launch_bounds__(256, 2)
void gemm_f16x3(const f16* __restrict__ Ahg, const f16* __restrict__ Alg,
                const f16* __restrict__ Bhg, const f16* __restrict__ Blg,
                const float* __restrict__ bias, float* __restrict__ C)
{
    __shared__ f16 Ah[128][32];
    __shared__ f16 Al[128][32];
    __shared__ f16 Bh[128][32];
    __shared__ f16 Bl[128][32];

    const int tid  = threadIdx.x;
    const int lane = tid & 63;
    const int wave = tid >> 6;
    const int wr   = wave >> 1;      // wave row (0..1) -> 64-row slab
    const int wc   = wave & 1;       // wave col (0..1) -> 64-col slab
    const int lr   = lane & 15;
    const int lq   = lane >> 4;
    const int bn   = blockIdx.x;
    const int bm   = blockIdx.y;

    f32x4 accH[4][4], accL[4][4];
#pragma unroll
    for (int i = 0; i < 4; ++i)
#pragma unroll
        for (int j = 0; j < 4; ++j) {
            accH[i][j] = (f32x4){0.f, 0.f, 0.f, 0.f};
            accL[i][j] = (f32x4){0.f, 0.f, 0.f, 0.f};
        }

    // Staging geometry: tile is 128 rows x 32 k (64B per row-line).
    // chunk c in [0,512): LDS byte off = c*16; global row = c>>2, byte-in-line = (c&3)*16.
    const int r0  = tid >> 2;
    const int r1  = (tid + 256) >> 2;
    const int cb  = (tid & 3) * 16;
    const char* ApH = (const char*)(Ahg + (size_t)(bm * 128) * IN_DIM);
    const char* ApL = (const char*)(Alg + (size_t)(bm * 128) * IN_DIM);
    const char* BpH = (const char*)(Bhg + (size_t)(bn * 128) * IN_DIM);
    const char* BpL = (const char*)(Blg + (size_t)(bn * 128) * IN_DIM);
    char* lAh = (char*)&Ah[0][0] + tid * 16;
    char* lAl = (char*)&Al[0][0] + tid * 16;
    char* lBh = (char*)&Bh[0][0] + tid * 16;
    char* lBl = (char*)&Bl[0][0] + tid * 16;

    for (int k0 = 0; k0 < IN_DIM; k0 += 32) {
        __syncthreads();
        const size_t o0 = (size_t)r0 * (IN_DIM * 2) + k0 * 2 + cb;
        const size_t o1 = (size_t)r1 * (IN_DIM * 2) + k0 * 2 + cb;
        GLDS16(ApH + o0, lAh);
        GLDS16(ApH + o1, lAh + 4096);
        GLDS16(ApL + o0, lAl);
        GLDS16(ApL + o1, lAl + 4096);
        GLDS16(BpH + o0, lBh);
        GLDS16(BpH + o1, lBh + 4096);
        GLDS16(BpL + o0, lBl);
        GLDS16(BpL + o1, lBl + 4096);
        __syncthreads();

        half8 a_h[4], a_l[4];
#pragma unroll
        for (int i = 0; i < 4; ++i) {
            const int row = wr * 64 + i * 16 + lr;
            a_h[i] = *reinterpret_cast<const half8*>(&Ah[row][lq * 8]);
            a_l[i] = *reinterpret_cast<const half8*>(&Al[row][lq * 8]);
        }
#pragma unroll
        for (int j = 0; j < 4; ++j) {
            const int col = wc * 64 + j * 16 + lr;
            const half8 b_h = *reinterpret_cast<const half8*>(&Bh[col][lq * 8]);
            const half8 b_l = *reinterpret_cast<const half8*>(&Bl[col][lq * 8]);
#pragma unroll
            for (int i = 0; i < 4; ++i)
                accH[i][j] = __builtin_amdgcn_mfma_f32_16x16x32_f16(a_h[i], b_h, accH[i][j], 0, 0, 0);
#pragma unroll
            for (int i = 0; i < 4; ++i)
                accL[i][j] = __builtin_amdgcn_mfma_f32_16x16x32_f16(a_l[i], b_h, accL[i][j], 0, 0, 0);
#pragma unroll
            for (int i = 0; i < 4; ++i)
                accL[i][j] = __builtin_amdgcn_mfma_f32_16x16x32_f16(a_h[i], b_l, accL[i][j], 0, 0, 0);
        }
    }

    // Epilogue: C/D layout col = lane&15, row = (lane>>4)*4 + reg [m89/m91].
    float bv[4];
#pragma unroll
    for (int j = 0; j < 4; ++j)
        bv[j] = bias[bn * 128 + wc * 64 + j * 16 + lr];
#pragma unroll
    for (int i = 0; i < 4; ++i) {
#pragma unroll
        for (int r = 0; r < 4; ++r) {
            const int row = bm * 128 + wr * 64 + i * 16 + lq * 4 + r;
            float* Cr = C + (size_t)row * OUT_DIM;
#pragma unroll
            for (int j = 0; j < 4; ++j) {
                const int col = bn * 128 + wc * 64 + j * 16 + lr;
                Cr[col] = accH[i][j][r] + 0.00048828125f * accL[i][j][r] + bv[j];
            }
        }
    }
}

// ---------------------------------------------------------------------------
// LIF scan over T with 16-deep load batching for latency hiding.
// ---------------------------------------------------------------------------
__global__ __launch_bounds__(256)
void lif_scan(const float* __restrict__ proj,
              float* __restrict__ out_mem, float* __restrict__ out_spk,
              int b_off)
{
    const int tid = blockIdx.x * 256 + threadIdx.x;
    const int b = tid >> 10;
    const int o = tid & 1023;
    const float* p = proj + (size_t)b * (T_STEPS * OUT_DIM) + o;

    float mem = 0.f, spk = 0.f;
    for (int t0 = 0; t0 < T_STEPS; t0 += 16) {
        float buf[16];
#pragma unroll
        for (int u = 0; u < 16; ++u)
            buf[u] = p[(size_t)(t0 + u) * OUT_DIM];
#pragma unroll
        for (int u = 0; u < 16; ++u) {
            mem = mem + (buf[u] - mem) * 0.5f;
            const bool fire = (mem >= 1.0f);
            spk = fire ? 1.0f : 0.0f;
            mem = fire ? 0.0f : mem;
        }
    }
    const size_t oi = (size_t)(b_off + b) * OUT_DIM + o;
    out_mem[oi] = mem;
    out_spk[oi] = spk;
}

// ---------------------------------------------------------------------------
extern "C" void kernel_launch(void* const* d_in, const int* in_sizes, int n_in,
                              void* d_out, int out_size, void* d_ws, size_t ws_size,
                              hipStream_t stream)
{
    const float* x    = (const float*)d_in[0];   // [64][512][1024] f32
    const float* W    = (const float*)d_in[1];   // [1024][1024] f32
    const float* bias = (const float*)d_in[2];   // [1024] f32

    float* out_mem = (float*)d_out;
    float* out_spk = out_mem + (size_t)B_TOTAL * OUT_DIM;

    const size_t MB = 1u << 20;
    char* ws = (char*)d_ws;
    f16* whi = (f16*)ws;                 // 2 MiB
    f16* wlo = (f16*)(ws + 2 * MB);      // 2 MiB
    char* base = ws + 4 * MB;

    // Per-batch chunk needs: xhi 1MB + xlo 1MB + proj 2MB = 4MB.
    int Bc = (int)((ws_size - 4 * MB) / (4 * MB));
    if (Bc > B_TOTAL) Bc = B_TOTAL;
    if (Bc < 1) Bc = 1;

    f16*   xhi  = (f16*)base;
    f16*   xlo  = (f16*)(base + (size_t)Bc * MB);
    float* proj = (float*)(base + 2 * (size_t)Bc * MB);

    // Split W once: 1024*1024/4 = 262144 float4 groups.
    split_f32_f16<<<1024, 256, 0, stream>>>(W, whi, wlo, 262144);

    for (int b0 = 0; b0 < B_TOTAL; b0 += Bc) {
        const int bc = (B_TOTAL - b0 < Bc) ? (B_TOTAL - b0) : Bc;
        // Split x chunk: bc*512*1024/4 float4 groups.
        split_f32_f16<<<bc * 512, 256, 0, stream>>>(
            x + (size_t)b0 * T_STEPS * IN_DIM, xhi, xlo, bc * 131072);
        // GEMM: grid (N tiles, M tiles) = (8, bc*4).
        gemm_f16x3<<<dim3(OUT_DIM / 128, bc * 4), 256, 0, stream>>>(
            xhi, xlo, whi, wlo, bias, proj);
        // Scan.
        lif_scan<<<bc * 4, 256, 0, stream>>>(proj, out_mem, out_spk, b0);
    }
}

// Round 3
// 467.543 us; speedup vs baseline: 2.1505x; 1.0028x over previous
//
#include <hip/hip_runtime.h>
#include <cstdint>
#include <cstddef>

typedef _Float16 f16;
typedef __attribute__((ext_vector_type(8))) _Float16 half8;
typedef __attribute__((ext_vector_type(4))) _Float16 half4;
typedef __attribute__((ext_vector_type(4))) float f32x4;

#define IN_DIM   1024
#define OUT_DIM  1024
#define T_STEPS  512
#define B_TOTAL  64
#define K3       3072
#define NTILES   48          // K3 / 64

#define RT2048   45.254833995939045f      // sqrt(2048)
#define IRT2048  0.0220970869120796f      // 1/sqrt(2048)

#define GLDS16(g, l)                                                            \
    __builtin_amdgcn_global_load_lds(                                           \
        (const __attribute__((address_space(1))) void*)(g),                     \
        (__attribute__((address_space(3))) void*)(l), 16, 0, 0)

#define MEMFENCE asm volatile("" ::: "memory")
#define SBAR     do { MEMFENCE; __builtin_amdgcn_s_barrier(); MEMFENCE; } while (0)
#define VMCNT(n) asm volatile("s_waitcnt vmcnt(" #n ")" ::: "memory")

// ---------------------------------------------------------------------------
// Split f32 -> 3-segment f16 row (K -> 3K).  mode 0 (x):  [h | s*lo | c*h]
//                                            mode 1 (W):  [h | c*h  | s*lo]
// s = sqrt(2048), c = 1/sqrt(2048); lo = (v - h) * 2048 pre-scale folded in.
// One thread = one float4 of input; blocks of 256 cover one 1024-row.
// ---------------------------------------------------------------------------
__global__ __launch_bounds__(256)
void split3(const float* __restrict__ in, f16* __restrict__ out, int mode)
{
    const int i4 = blockIdx.x * 256 + threadIdx.x;
    const int m  = i4 >> 8;
    const int kc = (i4 & 255) * 4;
    const float4 v = reinterpret_cast<const float4*>(in)[i4];
    const float xs[4] = { v.x, v.y, v.z, v.w };
    half4 h, lo, ch;
#pragma unroll
    for (int e = 0; e < 4; ++e) {
        const f16 hh = (f16)xs[e];
        h[e]  = hh;
        lo[e] = (f16)((xs[e] - (float)hh) * RT2048 * 2048.0f * (1.0f / 2048.0f) * RT2048);
        // note: (x-h)*sqrt(2048) exactly; written explicitly below instead
        lo[e] = (f16)((xs[e] - (float)hh) * RT2048);
        ch[e] = (f16)((float)hh * IRT2048);
    }
    f16* row = out + (size_t)m * K3;
    *reinterpret_cast<half4*>(row + kc)                    = h;
    *reinterpret_cast<half4*>(row + 1024 + kc)             = mode ? ch : lo;
    *reinterpret_cast<half4*>(row + 2048 + kc)             = mode ? lo : ch;
}

// ---------------------------------------------------------------------------
// 256x256 8-phase f16 GEMM, K = 3072 (packed 3-way split).
// C[m][n] = sum_k A'[m][k] * B'[n][k] + bias[n]
// 512 threads (8 waves, 2M x 4N), BK=64, 128 KiB LDS double buffer,
// counted vmcnt(4), XOR-swizzled LDS, setprio around MFMA, XCD swizzle.
// ---------------------------------------------------------------------------
__global__ __launch_bounds__(512, 2)
void gemm8(const f16* __restrict__ Ap, const f16* __restrict__ Bp,
           const float* __restrict__ bias, float* __restrict__ C, int cpx)
{
    extern __shared__ char smem[];   // [2][ As 32KB | Bs 32KB ] = 128 KiB

    const int tid  = threadIdx.x;
    const int lane = tid & 63;
    const int wave = tid >> 6;
    const int wm   = wave >> 2;      // 0..1: 128-row slab
    const int wn   = wave & 3;       // 0..3: 64-col slab
    const int lr   = lane & 15;
    const int lq16 = (lane >> 4) * 16;
    const int rsw  = (lr & 1) << 6;  // read-side XOR swizzle (row parity -> bit6)

    // XCD-aware bijective swizzle (nwg = 8*cpx, divisible by 8).
    const int bid = blockIdx.x;
    const int swz = (bid & 7) * cpx + (bid >> 3);
    const int mt  = swz >> 2;
    const int nt  = swz & 3;

    const f16* Ag = Ap + (size_t)(mt * 256) * K3;
    const f16* Bg = Bp + (size_t)(nt * 256) * K3;

#define STAGE(bufb, isB, j, kt) do {                                            \
        const int Drel_ = (j) * 8192 + tid * 16;                                \
        const int rw_   = Drel_ >> 7;                                           \
        const int kb_   = (Drel_ & 127) ^ ((rw_ & 1) << 6);                     \
        const char* g_  = (const char*)((isB) ? Bg : Ag)                        \
                          + (size_t)rw_ * (K3 * 2) + (kt) * 128 + kb_;          \
        GLDS16(g_, smem + (bufb) * 65536 + (isB) * 32768 + Drel_);              \
    } while (0)

#define LDS_A(bufb, row, ks) \
    (*(const half8*)(smem + (bufb) * 65536 + (row) * 128 + (((ks) * 64 + lq16) ^ rsw)))
#define LDS_B(bufb, row, ks) \
    (*(const half8*)(smem + (bufb) * 65536 + 32768 + (row) * 128 + (((ks) * 64 + lq16) ^ rsw)))

    f32x4 acc[8][4];
#pragma unroll
    for (int i = 0; i < 8; ++i)
#pragma unroll
        for (int j = 0; j < 4; ++j) acc[i][j] = (f32x4){0.f, 0.f, 0.f, 0.f};

    // Prologue: A(0), B(0) -> buf0; B(1) -> buf1.  vmcnt(4) leaves B(1) in flight.
    STAGE(0, 0, 0, 0); STAGE(0, 0, 1, 0); STAGE(0, 0, 2, 0); STAGE(0, 0, 3, 0);
    STAGE(0, 1, 0, 0); STAGE(0, 1, 1, 0); STAGE(0, 1, 2, 0); STAGE(0, 1, 3, 0);
    STAGE(1, 1, 0, 1); STAGE(1, 1, 1, 1); STAGE(1, 1, 2, 1); STAGE(1, 1, 3, 1);
    VMCNT(4);
    SBAR;

    half8 a_[4][2], bf[4][2];

    for (int t = 0; t < NTILES; ++t) {
        const int cur = t & 1;
        const int nxt = cur ^ 1;

        // ---- phase 1: read a[0:4] ks0+ks1, b[0:4] ks0; stage A0(t+1)
#pragma unroll
        for (int i = 0; i < 4; ++i) {
            const int row = wm * 128 + i * 16 + lr;
            a_[i][0] = LDS_A(cur, row, 0);
            a_[i][1] = LDS_A(cur, row, 1);
        }
#pragma unroll
        for (int j = 0; j < 4; ++j)
            bf[j][0] = LDS_B(cur, wn * 64 + j * 16 + lr, 0);
        if (t + 1 < NTILES) { STAGE(nxt, 0, 0, t + 1); STAGE(nxt, 0, 1, t + 1); }
        SBAR;
        __builtin_amdgcn_s_setprio(1);
#pragma unroll
        for (int j = 0; j < 4; ++j)
#pragma unroll
            for (int i = 0; i < 4; ++i)
                acc[i][j] = __builtin_amdgcn_mfma_f32_16x16x32_f16(a_[i][0], bf[j][0], acc[i][j], 0, 0, 0);
        __builtin_amdgcn_s_setprio(0);
        SBAR;

        // ---- phase 2: read b[0:4] ks1; stage A1(t+1)
#pragma unroll
        for (int j = 0; j < 4; ++j)
            bf[j][1] = LDS_B(cur, wn * 64 + j * 16 + lr, 1);
        if (t + 1 < NTILES) { STAGE(nxt, 0, 2, t + 1); STAGE(nxt, 0, 3, t + 1); }
        SBAR;
        __builtin_amdgcn_s_setprio(1);
#pragma unroll
        for (int j = 0; j < 4; ++j)
#pragma unroll
            for (int i = 0; i < 4; ++i)
                acc[i][j] = __builtin_amdgcn_mfma_f32_16x16x32_f16(a_[i][1], bf[j][1], acc[i][j], 0, 0, 0);
        __builtin_amdgcn_s_setprio(0);
        SBAR;

        // ---- phase 3: read a[4:8] ks0+ks1; stage B0(t+2) (B region consumed in ph2)
#pragma unroll
        for (int i = 0; i < 4; ++i) {
            const int row = wm * 128 + 64 + i * 16 + lr;
            a_[i][0] = LDS_A(cur, row, 0);
            a_[i][1] = LDS_A(cur, row, 1);
        }
        if (t + 2 < NTILES) { STAGE(cur, 1, 0, t + 2); STAGE(cur, 1, 1, t + 2); }
        SBAR;
        __builtin_amdgcn_s_setprio(1);
#pragma unroll
        for (int j = 0; j < 4; ++j)
#pragma unroll
            for (int i = 0; i < 4; ++i)
                acc[4 + i][j] = __builtin_amdgcn_mfma_f32_16x16x32_f16(a_[i][0], bf[j][0], acc[4 + i][j], 0, 0, 0);
        __builtin_amdgcn_s_setprio(0);
        SBAR;

        // ---- phase 4: stage B1(t+2); counted vmcnt -> tile t+1 landed
        if (t + 2 < NTILES) { STAGE(cur, 1, 2, t + 2); STAGE(cur, 1, 3, t + 2); }
        if (t < NTILES - 2) { VMCNT(4); } else { VMCNT(0); }
        SBAR;
        __builtin_amdgcn_s_setprio(1);
#pragma unroll
        for (int j = 0; j < 4; ++j)
#pragma unroll
            for (int i = 0; i < 4; ++i)
                acc[4 + i][j] = __builtin_amdgcn_mfma_f32_16x16x32_f16(a_[i][1], bf[j][1], acc[4 + i][j], 0, 0, 0);
        __builtin_amdgcn_s_setprio(0);
        SBAR;
    }

    // Epilogue: C/D layout col = lane&15, row = (lane>>4)*4 + reg  [m89/m91].
    float bv[4];
#pragma unroll
    for (int j = 0; j < 4; ++j)
        bv[j] = bias[nt * 256 + wn * 64 + j * 16 + lr];
    const int lq4 = (lane >> 4) * 4;
#pragma unroll
    for (int i = 0; i < 8; ++i) {
#pragma unroll
        for (int r = 0; r < 4; ++r) {
            const int row = mt * 256 + wm * 128 + i * 16 + lq4 + r;
            float* Cr = C + (size_t)row * OUT_DIM + nt * 256 + wn * 64;
#pragma unroll
            for (int j = 0; j < 4; ++j)
                Cr[j * 16 + lr] = acc[i][j][r] + bv[j];
        }
    }
#undef STAGE
#undef LDS_A
#undef LDS_B
}

// ---------------------------------------------------------------------------
// LIF scan, LDS-staged + double-buffered via global_load_lds, counted vmcnt.
// Block = (b, 256-o quarter). 16 segments of 32 timesteps.
// ---------------------------------------------------------------------------
__global__ __launch_bounds__(256)
void lif_scan(const float* __restrict__ proj,
              float* __restrict__ out_mem, float* __restrict__ out_spk,
              int b_off)
{
    __shared__ float sbuf[2][32][256];   // 64 KiB

    const int tid = threadIdx.x;
    const int blk = blockIdx.x;
    const int b   = blk >> 2;
    const int o0  = (blk & 3) * 256;
    const float* pb = proj + (size_t)b * (T_STEPS * OUT_DIM);

#define SCAN_STAGE(bufb, s) do {                                                \
        _Pragma("unroll")                                                       \
        for (int u = 0; u < 8; ++u) {                                           \
            const int tt = u * 4 + (tid >> 6);                                  \
            const int oc = (tid * 4) & 255;                                     \
            const float* g_ = pb + (size_t)((s) * 32 + tt) * OUT_DIM + o0 + oc; \
            GLDS16(g_, (char*)&sbuf[bufb][0][0] + u * 4096 + tid * 16);         \
        }                                                                       \
    } while (0)

    SCAN_STAGE(0, 0);

    float mem = 0.f, spk = 0.f;
    for (int s = 0; s < 16; ++s) {
        const int cur = s & 1;
        if (s + 1 < 16) { SCAN_STAGE(cur ^ 1, s + 1); VMCNT(8); }
        else            { VMCNT(0); }
        SBAR;
#pragma unroll
        for (int u = 0; u < 32; ++u) {
            const float in = sbuf[cur][u][tid];
            mem = mem + (in - mem) * 0.5f;           // TAU = 2.0
            const bool fire = (mem >= 1.0f);         // THRESHOLD = 1.0
            spk = fire ? 1.0f : 0.0f;
            mem = fire ? 0.0f : mem;
        }
        SBAR;
    }
    const size_t oi = (size_t)(b_off + b) * OUT_DIM + o0 + tid;
    out_mem[oi] = mem;
    out_spk[oi] = spk;
#undef SCAN_STAGE
}

// ---------------------------------------------------------------------------
extern "C" void kernel_launch(void* const* d_in, const int* in_sizes, int n_in,
                              void* d_out, int out_size, void* d_ws, size_t ws_size,
                              hipStream_t stream)
{
    const float* x    = (const float*)d_in[0];   // [64][512][1024] f32
    const float* W    = (const float*)d_in[1];   // [1024][1024] f32
    const float* bias = (const float*)d_in[2];   // [1024] f32

    float* out_mem = (float*)d_out;
    float* out_spk = out_mem + (size_t)B_TOTAL * OUT_DIM;

    const size_t MB = 1u << 20;
    char* ws = (char*)d_ws;
    f16* Bp = (f16*)ws;                          // B' [1024][3072] f16 = 6 MiB
    char* base = ws + 6 * MB;

    // Per-batch chunk: A' 512x3072 f16 = 3 MiB + proj 512x1024 f32 = 2 MiB.
    int Bc = (int)((ws_size - 6 * MB) / (5 * MB));
    if (Bc > B_TOTAL) Bc = B_TOTAL;
    if (Bc < 1) Bc = 1;

    f16*   Apx  = (f16*)base;                                  // Bc * 3 MiB
    float* proj = (float*)(base + (size_t)Bc * 3 * MB);        // Bc * 2 MiB

    // Build B' once: 1024 rows -> 1024 blocks.
    split3<<<1024, 256, 0, stream>>>(W, Bp, 1);

    for (int b0 = 0; b0 < B_TOTAL; b0 += Bc) {
        const int bc = (B_TOTAL - b0 < Bc) ? (B_TOTAL - b0) : Bc;
        // A' for bc*512 rows.
        split3<<<bc * 512, 256, 0, stream>>>(
            x + (size_t)b0 * T_STEPS * IN_DIM, Apx, 0);
        // GEMM: M-tiles = bc*2, N-tiles = 4 -> nwg = 8*bc (divisible by 8).
        const int nwg = bc * 8;
        gemm8<<<nwg, 512, 131072, stream>>>(Apx, Bp, bias, proj, nwg / 8);
        // Scan.
        lif_scan<<<bc * 4, 256, 0, stream>>>(proj, out_mem, out_spk, b0);
    }
}

// Round 4
// 431.166 us; speedup vs baseline: 2.3320x; 1.0844x over previous
//
#include <hip/hip_runtime.h>
#include <cstdint>
#include <cstddef>

typedef _Float16 f16;
typedef __attribute__((ext_vector_type(8))) _Float16 half8;
typedef __attribute__((ext_vector_type(4))) _Float16 half4;
typedef __attribute__((ext_vector_type(4))) float f32x4;

#define IN_DIM   1024
#define OUT_DIM  1024
#define T_STEPS  512
#define B_TOTAL  64
#define K3       3072
#define NTILES   48          // K3 / 64

#define RT2048   45.254833995939045f      // sqrt(2048)
#define IRT2048  0.0220970869120796f      // 1/sqrt(2048)

#define GLDS16(g, l)                                                            \
    __builtin_amdgcn_global_load_lds(                                           \
        (const __attribute__((address_space(1))) void*)(g),                     \
        (__attribute__((address_space(3))) void*)(l), 16, 0, 0)

#define MEMFENCE asm volatile("" ::: "memory")
#define SBAR     do { MEMFENCE; __builtin_amdgcn_s_barrier(); MEMFENCE; } while (0)
#define VMCNT(n) asm volatile("s_waitcnt vmcnt(" #n ")" ::: "memory")

// ---------------------------------------------------------------------------
// Split f32 -> 3-segment f16 row (K -> 3K).  mode 0 (x):  [h | s*lo | c*h]
//                                            mode 1 (W):  [h | c*h  | s*lo]
// s = sqrt(2048), c = 1/sqrt(2048), lo = (v - h).  s*c = 1, so
//   A'.B' = h_x*h_w + (x-h_x)*h_w + h_x*(w-h_w)   (exact f32-level split).
// One thread = 8 consecutive elems; 16B half8 stores per segment.
// ---------------------------------------------------------------------------
__global__ __launch_bounds__(256)
void split3(const float* __restrict__ in, f16* __restrict__ out, int mode)
{
    const int i8 = blockIdx.x * 256 + threadIdx.x;
    const int m  = i8 >> 7;              // row (128 groups of 8 per 1024-row)
    const int kc = (i8 & 127) * 8;
    const float4 v0 = reinterpret_cast<const float4*>(in)[i8 * 2];
    const float4 v1 = reinterpret_cast<const float4*>(in)[i8 * 2 + 1];
    const float xs[8] = { v0.x, v0.y, v0.z, v0.w, v1.x, v1.y, v1.z, v1.w };
    half8 h, lo, ch;
#pragma unroll
    for (int e = 0; e < 8; ++e) {
        const f16 hh = (f16)xs[e];
        h[e]  = hh;
        lo[e] = (f16)((xs[e] - (float)hh) * RT2048);
        ch[e] = (f16)((float)hh * IRT2048);
    }
    f16* row = out + (size_t)m * K3;
    *reinterpret_cast<half8*>(row + kc)        = h;
    *reinterpret_cast<half8*>(row + 1024 + kc) = mode ? ch : lo;
    *reinterpret_cast<half8*>(row + 2048 + kc) = mode ? lo : ch;
}

// ---------------------------------------------------------------------------
// 256x256 8-phase f16 GEMM, K = 3072 (packed 3-way split).
// C[m][n] = sum_k A'[m][k] * B'[n][k] + bias[n]
// 512 threads (8 waves, 2M x 4N), BK=64, 128 KiB LDS double buffer,
// counted vmcnt(4), conflict-free (row&7)<<4 XOR swizzle (T2), setprio (T5),
// XCD swizzle (T1).
// ---------------------------------------------------------------------------
__global__ __launch_bounds__(512, 2)
void gemm8(const f16* __restrict__ Ap, const f16* __restrict__ Bp,
           const float* __restrict__ bias, float* __restrict__ C, int cpx)
{
    extern __shared__ char smem[];   // [2][ As 32KB | Bs 32KB ] = 128 KiB

    const int tid  = threadIdx.x;
    const int lane = tid & 63;
    const int wave = tid >> 6;
    const int wm   = wave >> 2;      // 0..1: 128-row slab
    const int wn   = wave & 3;       // 0..3: 64-col slab
    const int lr   = lane & 15;
    const int lq16 = (lane >> 4) * 16;
    const int rsw  = (lr & 7) << 4;  // read-side XOR swizzle: row&7 -> 16B slot

    // XCD-aware bijective swizzle (nwg = 8*cpx, divisible by 8).
    const int bid = blockIdx.x;
    const int swz = (bid & 7) * cpx + (bid >> 3);
    const int mt  = swz >> 2;
    const int nt  = swz & 3;

    const f16* Ag = Ap + (size_t)(mt * 256) * K3;
    const f16* Bg = Bp + (size_t)(nt * 256) * K3;

    // Write side: LDS dest is linear (gload_lds constraint); the SOURCE k-byte
    // is inverse-swizzled with the same involution the reads apply (rule #21).
#define STAGE(bufb, isB, j, kt) do {                                            \
        const int Drel_ = (j) * 8192 + tid * 16;                                \
        const int rw_   = Drel_ >> 7;                                           \
        const int kb_   = (Drel_ & 127) ^ ((rw_ & 7) << 4);                     \
        const char* g_  = (const char*)((isB) ? Bg : Ag)                        \
                          + (size_t)rw_ * (K3 * 2) + (kt) * 128 + kb_;          \
        GLDS16(g_, smem + (bufb) * 65536 + (isB) * 32768 + Drel_);              \
    } while (0)

#define LDS_A(bufb, row, ks) \
    (*(const half8*)(smem + (bufb) * 65536 + (row) * 128 + (((ks) * 64 + lq16) ^ rsw)))
#define LDS_B(bufb, row, ks) \
    (*(const half8*)(smem + (bufb) * 65536 + 32768 + (row) * 128 + (((ks) * 64 + lq16) ^ rsw)))

    f32x4 acc[8][4];
#pragma unroll
    for (int i = 0; i < 8; ++i)
#pragma unroll
        for (int j = 0; j < 4; ++j) acc[i][j] = (f32x4){0.f, 0.f, 0.f, 0.f};

    // Prologue: A(0), B(0) -> buf0; B(1) -> buf1.  vmcnt(4) leaves B(1) in flight.
    STAGE(0, 0, 0, 0); STAGE(0, 0, 1, 0); STAGE(0, 0, 2, 0); STAGE(0, 0, 3, 0);
    STAGE(0, 1, 0, 0); STAGE(0, 1, 1, 0); STAGE(0, 1, 2, 0); STAGE(0, 1, 3, 0);
    STAGE(1, 1, 0, 1); STAGE(1, 1, 1, 1); STAGE(1, 1, 2, 1); STAGE(1, 1, 3, 1);
    VMCNT(4);
    SBAR;

    half8 a_[4][2], bf[4][2];

    for (int t = 0; t < NTILES; ++t) {
        const int cur = t & 1;
        const int nxt = cur ^ 1;

        // ---- phase 1: read a[0:4] ks0+ks1, b[0:4] ks0; stage A0(t+1)
#pragma unroll
        for (int i = 0; i < 4; ++i) {
            const int row = wm * 128 + i * 16 + lr;
            a_[i][0] = LDS_A(cur, row, 0);
            a_[i][1] = LDS_A(cur, row, 1);
        }
#pragma unroll
        for (int j = 0; j < 4; ++j)
            bf[j][0] = LDS_B(cur, wn * 64 + j * 16 + lr, 0);
        if (t + 1 < NTILES) { STAGE(nxt, 0, 0, t + 1); STAGE(nxt, 0, 1, t + 1); }
        SBAR;
        __builtin_amdgcn_s_setprio(1);
#pragma unroll
        for (int j = 0; j < 4; ++j)
#pragma unroll
            for (int i = 0; i < 4; ++i)
                acc[i][j] = __builtin_amdgcn_mfma_f32_16x16x32_f16(a_[i][0], bf[j][0], acc[i][j], 0, 0, 0);
        __builtin_amdgcn_s_setprio(0);
        SBAR;

        // ---- phase 2: read b[0:4] ks1; stage A1(t+1)
#pragma unroll
        for (int j = 0; j < 4; ++j)
            bf[j][1] = LDS_B(cur, wn * 64 + j * 16 + lr, 1);
        if (t + 1 < NTILES) { STAGE(nxt, 0, 2, t + 1); STAGE(nxt, 0, 3, t + 1); }
        SBAR;
        __builtin_amdgcn_s_setprio(1);
#pragma unroll
        for (int j = 0; j < 4; ++j)
#pragma unroll
            for (int i = 0; i < 4; ++i)
                acc[i][j] = __builtin_amdgcn_mfma_f32_16x16x32_f16(a_[i][1], bf[j][1], acc[i][j], 0, 0, 0);
        __builtin_amdgcn_s_setprio(0);
        SBAR;

        // ---- phase 3: read a[4:8] ks0+ks1; stage B0(t+2) (B region consumed in ph2)
#pragma unroll
        for (int i = 0; i < 4; ++i) {
            const int row = wm * 128 + 64 + i * 16 + lr;
            a_[i][0] = LDS_A(cur, row, 0);
            a_[i][1] = LDS_A(cur, row, 1);
        }
        if (t + 2 < NTILES) { STAGE(cur, 1, 0, t + 2); STAGE(cur, 1, 1, t + 2); }
        SBAR;
        __builtin_amdgcn_s_setprio(1);
#pragma unroll
        for (int j = 0; j < 4; ++j)
#pragma unroll
            for (int i = 0; i < 4; ++i)
                acc[4 + i][j] = __builtin_amdgcn_mfma_f32_16x16x32_f16(a_[i][0], bf[j][0], acc[4 + i][j], 0, 0, 0);
        __builtin_amdgcn_s_setprio(0);
        SBAR;

        // ---- phase 4: stage B1(t+2); counted vmcnt -> tile t+1 landed
        if (t + 2 < NTILES) { STAGE(cur, 1, 2, t + 2); STAGE(cur, 1, 3, t + 2); }
        if (t < NTILES - 2) { VMCNT(4); } else { VMCNT(0); }
        SBAR;
        __builtin_amdgcn_s_setprio(1);
#pragma unroll
        for (int j = 0; j < 4; ++j)
#pragma unroll
            for (int i = 0; i < 4; ++i)
                acc[4 + i][j] = __builtin_amdgcn_mfma_f32_16x16x32_f16(a_[i][1], bf[j][1], acc[4 + i][j], 0, 0, 0);
        __builtin_amdgcn_s_setprio(0);
        SBAR;
    }

    // Epilogue: C/D layout col = lane&15, row = (lane>>4)*4 + reg  [m89/m91].
    float bv[4];
#pragma unroll
    for (int j = 0; j < 4; ++j)
        bv[j] = bias[nt * 256 + wn * 64 + j * 16 + lr];
    const int lq4 = (lane >> 4) * 4;
#pragma unroll
    for (int i = 0; i < 8; ++i) {
#pragma unroll
        for (int r = 0; r < 4; ++r) {
            const int row = mt * 256 + wm * 128 + i * 16 + lq4 + r;
            float* Cr = C + (size_t)row * OUT_DIM + nt * 256 + wn * 64;
#pragma unroll
            for (int j = 0; j < 4; ++j)
                Cr[j * 16 + lr] = acc[i][j][r] + bv[j];
        }
    }
#undef STAGE
#undef LDS_A
#undef LDS_B
}

// ---------------------------------------------------------------------------
// LIF scan, LDS-staged + double-buffered via global_load_lds, counted vmcnt.
// Block = (b, 256-o quarter). 16 segments of 32 timesteps.
// ---------------------------------------------------------------------------
__global__ __launch_bounds__(256)
void lif_scan(const float* __restrict__ proj,
              float* __restrict__ out_mem, float* __restrict__ out_spk,
              int b_off)
{
    __shared__ float sbuf[2][32][256];   // 64 KiB

    const int tid = threadIdx.x;
    const int blk = blockIdx.x;
    const int b   = blk >> 2;
    const int o0  = (blk & 3) * 256;
    const float* pb = proj + (size_t)b * (T_STEPS * OUT_DIM);

#define SCAN_STAGE(bufb, s) do {                                                \
        _Pragma("unroll")                                                       \
        for (int u = 0; u < 8; ++u) {                                           \
            const int tt = u * 4 + (tid >> 6);                                  \
            const int oc = (tid * 4) & 255;                                     \
            const float* g_ = pb + (size_t)((s) * 32 + tt) * OUT_DIM + o0 + oc; \
            GLDS16(g_, (char*)&sbuf[bufb][0][0] + u * 4096 + tid * 16);         \
        }                                                                       \
    } while (0)

    SCAN_STAGE(0, 0);

    float mem = 0.f, spk = 0.f;
    for (int s = 0; s < 16; ++s) {
        const int cur = s & 1;
        if (s + 1 < 16) { SCAN_STAGE(cur ^ 1, s + 1); VMCNT(8); }
        else            { VMCNT(0); }
        SBAR;
#pragma unroll
        for (int u = 0; u < 32; ++u) {
            const float in = sbuf[cur][u][tid];
            mem = mem + (in - mem) * 0.5f;           // TAU = 2.0
            const bool fire = (mem >= 1.0f);         // THRESHOLD = 1.0
            spk = fire ? 1.0f : 0.0f;
            mem = fire ? 0.0f : mem;
        }
        SBAR;
    }
    const size_t oi = (size_t)(b_off + b) * OUT_DIM + o0 + tid;
    out_mem[oi] = mem;
    out_spk[oi] = spk;
#undef SCAN_STAGE
}

// ---------------------------------------------------------------------------
extern "C" void kernel_launch(void* const* d_in, const int* in_sizes, int n_in,
                              void* d_out, int out_size, void* d_ws, size_t ws_size,
                              hipStream_t stream)
{
    const float* x    = (const float*)d_in[0];   // [64][512][1024] f32
    const float* W    = (const float*)d_in[1];   // [1024][1024] f32
    const float* bias = (const float*)d_in[2];   // [1024] f32

    float* out_mem = (float*)d_out;
    float* out_spk = out_mem + (size_t)B_TOTAL * OUT_DIM;

    const size_t MB = 1u << 20;
    char* ws = (char*)d_ws;
    f16* Bp = (f16*)ws;                          // B' [1024][3072] f16 = 6 MiB
    char* base = ws + 6 * MB;

    // Per-batch chunk: A' 512x3072 f16 = 3 MiB + proj 512x1024 f32 = 2 MiB.
    int Bc = (int)((ws_size - 6 * MB) / (5 * MB));
    if (Bc > B_TOTAL) Bc = B_TOTAL;
    if (Bc < 1) Bc = 1;

    f16*   Apx  = (f16*)base;                                  // Bc * 3 MiB
    float* proj = (float*)(base + (size_t)Bc * 3 * MB);        // Bc * 2 MiB

    // Build B' once: 1024 rows x 128 groups / 256 threads = 512 blocks.
    split3<<<512, 256, 0, stream>>>(W, Bp, 1);

    for (int b0 = 0; b0 < B_TOTAL; b0 += Bc) {
        const int bc = (B_TOTAL - b0 < Bc) ? (B_TOTAL - b0) : Bc;
        // A' for bc*512 rows: bc*512*128/256 = bc*256 blocks.
        split3<<<bc * 256, 256, 0, stream>>>(
            x + (size_t)b0 * T_STEPS * IN_DIM, Apx, 0);
        // GEMM: M-tiles = bc*2, N-tiles = 4 -> nwg = 8*bc (divisible by 8).
        const int nwg = bc * 8;
        gemm8<<<nwg, 512, 131072, stream>>>(Apx, Bp, bias, proj, nwg / 8);
        // Scan.
        lif_scan<<<bc * 4, 256, 0, stream>>>(proj, out_mem, out_spk, b0);
    }
}